// Round 1
// baseline (328.456 us; speedup 1.0000x reference)
//
#include <hip/hip_runtime.h>
#include <hip/hip_bf16.h>
#include <cstdint>

// Problem sizes (fixed by reference setup_inputs)
#define B_SZ 8192
#define F_SZ 4096
#define D_SZ 1024
#define K_SZ 2048  // 2*D : A = [x^2 | x], W = [inv2 | -2*mu*inv2]

typedef __bf16 bf16x8 __attribute__((ext_vector_type(8)));
typedef float f32x4 __attribute__((ext_vector_type(4)));

// round-to-nearest-even fp32 -> bf16 bits
__device__ __forceinline__ unsigned short f2bf(float f) {
    union { float f; unsigned u; } c; c.f = f;
    unsigned r = c.u + 0x7fff + ((c.u >> 16) & 1);
    return (unsigned short)(r >> 16);
}

// async global->LDS, 16 B per lane; LDS dest = wave-uniform base + lane*16
__device__ __forceinline__ void async16(const void* g, void* l) {
    __builtin_amdgcn_global_load_lds(
        (__attribute__((address_space(1))) void*)g,
        (__attribute__((address_space(3))) void*)l, 16, 0, 0);
}

// K1: A[b, 0:1024] = bf16(x^2), A[b, 1024:2048] = bf16(x)
__global__ __launch_bounds__(256) void prep_a(const float* __restrict__ x,
                                              unsigned short* __restrict__ A) {
    int gid = blockIdx.x * 256 + threadIdx.x;   // one float4 per thread
    int idx4 = gid * 4;
    int b = idx4 >> 10;
    int d = idx4 & 1023;
    float4 v = *(const float4*)(x + idx4);
    ushort4 xx, xs;
    xx.x = f2bf(v.x * v.x); xx.y = f2bf(v.y * v.y);
    xx.z = f2bf(v.z * v.z); xx.w = f2bf(v.w * v.w);
    xs.x = f2bf(v.x); xs.y = f2bf(v.y); xs.z = f2bf(v.z); xs.w = f2bf(v.w);
    size_t base = (size_t)b * K_SZ;
    *(ushort4*)(A + base + d) = xx;
    *(ushort4*)(A + base + 1024 + d) = xs;
}

// K2: W[f, 0:1024] = bf16(inv2), W[f, 1024:2048] = bf16(-2*mu*inv2),
//     nmm[f] = -0.5 * sum_d mu^2 * inv2   (fp32)
__global__ __launch_bounds__(256) void prep_w(const float* __restrict__ mu,
                                              const float* __restrict__ sd,
                                              unsigned short* __restrict__ W,
                                              float* __restrict__ nmm) {
    int f = blockIdx.x;
    int d = threadIdx.x * 4;           // 256 threads * 4 = 1024 cols, one pass
    size_t off = (size_t)f * D_SZ + d;
    float4 m = *(const float4*)(mu + off);
    float4 s = *(const float4*)(sd + off);
    float i0 = 1.0f / (s.x * s.x), i1 = 1.0f / (s.y * s.y);
    float i2 = 1.0f / (s.z * s.z), i3 = 1.0f / (s.w * s.w);
    ushort4 wi, wm;
    wi.x = f2bf(i0); wi.y = f2bf(i1); wi.z = f2bf(i2); wi.w = f2bf(i3);
    wm.x = f2bf(-2.0f * m.x * i0); wm.y = f2bf(-2.0f * m.y * i1);
    wm.z = f2bf(-2.0f * m.z * i2); wm.w = f2bf(-2.0f * m.w * i3);
    size_t wb = (size_t)f * K_SZ + d;
    *(ushort4*)(W + wb) = wi;
    *(ushort4*)(W + wb + 1024) = wm;
    float mm = m.x * m.x * i0 + m.y * m.y * i1 + m.z * m.z * i2 + m.w * m.w * i3;
    #pragma unroll
    for (int o = 32; o > 0; o >>= 1) mm += __shfl_down(mm, o, 64);
    __shared__ float red[4];
    if ((threadIdx.x & 63) == 0) red[threadIdx.x >> 6] = mm;
    __syncthreads();
    if (threadIdx.x == 0) nmm[f] = -0.5f * (red[0] + red[1] + red[2] + red[3]);
}

// GEMM: out[b,f] = -0.5 * (A @ W^T)[b,f] + nmm[f]
// m97 structure: 128x128 tile, BK=32, 4 waves, 4x4 16x16x32 bf16 MFMA frags/wave
__global__ __launch_bounds__(256) void gemm_bt(const unsigned short* __restrict__ A,
                                               const unsigned short* __restrict__ W,
                                               const float* __restrict__ nmm,
                                               float* __restrict__ out) {
    // row-major [128 rows][32 k] bf16 tiles; layout forced by global_load_lds
    // (wave-uniform base + lane*16) -- no padding possible.
    __shared__ __align__(16) unsigned short sA[128 * 32];
    __shared__ __align__(16) unsigned short sB[128 * 32];

    const int tid  = threadIdx.x;
    const int wave = tid >> 6;
    const int lane = tid & 63;
    const int wm = (wave >> 1) * 64;   // wave's m-offset in tile
    const int wn = (wave & 1) * 64;    // wave's n-offset in tile
    const int tileM = blockIdx.y * 128;
    const int tileN = blockIdx.x * 128;
    const int r16  = lane & 15;
    const int quad = lane >> 4;

    // staging coords: issue i, thread t covers elements flat=(i*256+t)*8 .. +7
    const int row0 = tid >> 2;                  // flat/32, i=0
    const int col0 = (tid & 3) * 8;             // flat%32
    unsigned short* ldsA0 = sA + (wave * 64) * 8;
    unsigned short* ldsA1 = sA + (256 + wave * 64) * 8;
    unsigned short* ldsB0 = sB + (wave * 64) * 8;
    unsigned short* ldsB1 = sB + (256 + wave * 64) * 8;

    const f32x4 vzero = {0.f, 0.f, 0.f, 0.f};
    f32x4 acc[4][4];
    #pragma unroll
    for (int i = 0; i < 4; ++i)
        #pragma unroll
        for (int j = 0; j < 4; ++j) acc[i][j] = vzero;

    for (int k0 = 0; k0 < K_SZ; k0 += 32) {
        async16(A + (size_t)(tileM + row0) * K_SZ + k0 + col0, ldsA0);
        async16(A + (size_t)(tileM + row0 + 64) * K_SZ + k0 + col0, ldsA1);
        async16(W + (size_t)(tileN + row0) * K_SZ + k0 + col0, ldsB0);
        async16(W + (size_t)(tileN + row0 + 64) * K_SZ + k0 + col0, ldsB1);
        __syncthreads();   // drains vmcnt: LDS tiles complete for all waves

        bf16x8 af[4], bfr[4];
        #pragma unroll
        for (int i = 0; i < 4; ++i)
            af[i] = *(const bf16x8*)(sA + (wm + i * 16 + r16) * 32 + quad * 8);
        #pragma unroll
        for (int j = 0; j < 4; ++j)
            bfr[j] = *(const bf16x8*)(sB + (wn + j * 16 + r16) * 32 + quad * 8);
        #pragma unroll
        for (int i = 0; i < 4; ++i)
            #pragma unroll
            for (int j = 0; j < 4; ++j)
                acc[i][j] = __builtin_amdgcn_mfma_f32_16x16x32_bf16(
                    af[i], bfr[j], acc[i][j], 0, 0, 0);
        __syncthreads();   // protect LDS before next iteration's staging
    }

    // epilogue: C/D layout col=lane&15, row=quad*4+reg
    int   fc[4];
    float cj[4];
    #pragma unroll
    for (int j = 0; j < 4; ++j) {
        fc[j] = tileN + wn + j * 16 + r16;
        cj[j] = nmm[fc[j]];
    }
    #pragma unroll
    for (int i = 0; i < 4; ++i) {
        int mbase = tileM + wm + i * 16 + quad * 4;
        #pragma unroll
        for (int r = 0; r < 4; ++r) {
            float* orow = out + (size_t)(mbase + r) * F_SZ;
            #pragma unroll
            for (int j = 0; j < 4; ++j)
                orow[fc[j]] = -0.5f * acc[i][j][r] + cj[j];
        }
    }
}

extern "C" void kernel_launch(void* const* d_in, const int* in_sizes, int n_in,
                              void* d_out, int out_size, void* d_ws, size_t ws_size,
                              hipStream_t stream) {
    const float* x  = (const float*)d_in[0];
    const float* mu = (const float*)d_in[1];
    const float* sd = (const float*)d_in[2];
    float* out = (float*)d_out;

    // workspace layout: A (8192x2048 bf16, 33.5 MB) | W (4096x2048 bf16, 16.8 MB) | nmm (16 KB)
    unsigned short* A = (unsigned short*)d_ws;
    unsigned short* W = A + (size_t)B_SZ * K_SZ;
    float* nmm = (float*)(W + (size_t)F_SZ * K_SZ);

    prep_a<<<(B_SZ * D_SZ) / (256 * 4), 256, 0, stream>>>(x, A);
    prep_w<<<F_SZ, 256, 0, stream>>>(mu, sd, W, nmm);
    gemm_bt<<<dim3(F_SZ / 128, B_SZ / 128), 256, 0, stream>>>(A, W, nmm, out);
}